// Round 4
// baseline (146.888 us; speedup 1.0000x reference)
//
#include <hip/hip_runtime.h>

// Problem constants
constexpr int B_TOT = 8192;      // batch
constexpr int NM    = 64;        // n_models
constexpr int TT    = 16;        // trees per split
constexpr int LF    = 64;        // maxleaf
constexpr int EM    = 32;        // emb dim
constexpr int XROW  = NM * TT;   // 1024 ints per x row
constexpr int TROWS = TT * LF;   // 1024 rows per model table

// ---------------------------------------------------------------------------
// K0: convert embed_w (f32, 8MB) -> bf16 (4MB), same [m][row][e] layout, RNE.
// Halves the per-row gather bytes in k_stats (128B -> 64B rows).
// Grid: 2048 x 256, one float4 -> ushort4 per thread (2M elems exactly).
// ---------------------------------------------------------------------------
__global__ __launch_bounds__(256) void k_conv(const float4* __restrict__ in,
                                              ushort4* __restrict__ out16) {
    const int i = blockIdx.x * 256 + threadIdx.x;
    const float4 v = in[i];
    unsigned ux = __float_as_uint(v.x), uy = __float_as_uint(v.y),
             uz = __float_as_uint(v.z), uw = __float_as_uint(v.w);
    ux += 0x7fffu + ((ux >> 16) & 1u);  uy += 0x7fffu + ((uy >> 16) & 1u);
    uz += 0x7fffu + ((uz >> 16) & 1u);  uw += 0x7fffu + ((uw >> 16) & 1u);
    ushort4 o;
    o.x = (unsigned short)(ux >> 16); o.y = (unsigned short)(uy >> 16);
    o.z = (unsigned short)(uz >> 16); o.w = (unsigned short)(uw >> 16);
    out16[i] = o;
}

__device__ __forceinline__ void accum8(float* h, const uint4 v) {
    // bf16 pair -> f32: lo = u<<16, hi = u & 0xffff0000 (free conversions)
    h[0] += __uint_as_float(v.x << 16);
    h[1] += __uint_as_float(v.x & 0xffff0000u);
    h[2] += __uint_as_float(v.y << 16);
    h[3] += __uint_as_float(v.y & 0xffff0000u);
    h[4] += __uint_as_float(v.z << 16);
    h[5] += __uint_as_float(v.z & 0xffff0000u);
    h[6] += __uint_as_float(v.w << 16);
    h[7] += __uint_as_float(v.w & 0xffff0000u);
}

// ---------------------------------------------------------------------------
// K1 (bf16): per-channel batch stats from the bf16 table.
// Lane layout: f = tid&3 (16B chunk = 8 channels), grp = tid>>2 (b-group).
// One dwordx4 gather now covers 16 rows x 64B (vs 8 x 128B in f32) ->
// 524K wave gathers total, 0.54 GB L2 traffic (was 1.05M / 1.07 GB).
// Grid: 2048 = 64 m x 32 chunks (256 b each); 4 b per thread.
// ---------------------------------------------------------------------------
__global__ __launch_bounds__(256) void k_stats16(
    const int* __restrict__ x, const uint4* __restrict__ tbl,
    float* __restrict__ wsum, float* __restrict__ wsumsq)
{
    const int m     = blockIdx.x & 63;
    const int chunk = blockIdx.x >> 6;      // 0..31
    const int f     = threadIdx.x & 3;      // uint4 within 64B row
    const int grp   = threadIdx.x >> 2;     // 0..63
    const uint4* __restrict__ tblr = tbl + (size_t)m * (TROWS * 4);
    const int b0 = chunk * 256 + grp * 4;
    const int* __restrict__ xb = x + (size_t)b0 * XROW + m * TT;

    float h[4][8];
#pragma unroll
    for (int i = 0; i < 4; ++i)
#pragma unroll
        for (int k = 0; k < 8; ++k) h[i][k] = 0.f;

#pragma unroll
    for (int tq = 0; tq < 4; ++tq) {
        const int rbase = tq * 256;
#pragma unroll
        for (int bb = 0; bb < 4; ++bb) {
            const int4 q = *(const int4*)(xb + (size_t)bb * XROW + tq * 4);
            const uint4 v0 = tblr[(q.x + rbase      ) * 4 + f];
            const uint4 v1 = tblr[(q.y + rbase +  64) * 4 + f];
            const uint4 v2 = tblr[(q.z + rbase + 128) * 4 + f];
            const uint4 v3 = tblr[(q.w + rbase + 192) * 4 + f];
            accum8(h[bb], v0); accum8(h[bb], v1);
            accum8(h[bb], v2); accum8(h[bb], v3);
        }
    }

    float s[8], s2[8];
#pragma unroll
    for (int k = 0; k < 8; ++k) {
        s[k]  = h[0][k] + h[1][k] + h[2][k] + h[3][k];
        s2[k] = h[0][k]*h[0][k] + h[1][k]*h[1][k]
              + h[2][k]*h[2][k] + h[3][k]*h[3][k];
    }

    __shared__ float ls[64][32];
    __shared__ float ls2[64][32];
#pragma unroll
    for (int k = 0; k < 8; ++k) { ls[grp][f*8+k] = s[k]; ls2[grp][f*8+k] = s2[k]; }
    __syncthreads();
    if (threadIdx.x < 32) {
        const int e = threadIdx.x;
        float a = 0.f, a2 = 0.f;
#pragma unroll
        for (int g = 0; g < 64; ++g) { a += ls[g][e]; a2 += ls2[g][e]; }
        atomicAdd(&wsum[m * EM + e], a);
        atomicAdd(&wsumsq[m * EM + e], a2);
    }
}

// ---------------------------------------------------------------------------
// K1-fallback (f32, round-3 version) if ws is too small for the bf16 table.
// ---------------------------------------------------------------------------
__global__ __launch_bounds__(256) void k_stats(
    const int* __restrict__ x, const float* __restrict__ tbl,
    float* __restrict__ wsum, float* __restrict__ wsumsq)
{
    const int m     = blockIdx.x & 63;
    const int chunk = blockIdx.x >> 6;
    const int f     = threadIdx.x & 7;
    const int grp   = threadIdx.x >> 3;
    const float4* __restrict__ tbl4 = (const float4*)(tbl + (size_t)m * (TROWS * EM));
    const int b0 = chunk * 128 + grp * 4;
    const int* __restrict__ xb = x + (size_t)b0 * XROW + m * TT;

    float4 h[4];
#pragma unroll
    for (int i = 0; i < 4; ++i) h[i] = make_float4(0.f, 0.f, 0.f, 0.f);
#pragma unroll
    for (int tq = 0; tq < 4; ++tq) {
        const int rbase = tq * 256;
#pragma unroll
        for (int bb = 0; bb < 4; ++bb) {
            const int4 q = *(const int4*)(xb + (size_t)bb * XROW + tq * 4);
            const float4 v0 = tbl4[(q.x + rbase      ) * 8 + f];
            const float4 v1 = tbl4[(q.y + rbase +  64) * 8 + f];
            const float4 v2 = tbl4[(q.z + rbase + 128) * 8 + f];
            const float4 v3 = tbl4[(q.w + rbase + 192) * 8 + f];
            h[bb].x += v0.x + v1.x + v2.x + v3.x;
            h[bb].y += v0.y + v1.y + v2.y + v3.y;
            h[bb].z += v0.z + v1.z + v2.z + v3.z;
            h[bb].w += v0.w + v1.w + v2.w + v3.w;
        }
    }
    float4 s  = make_float4(0.f,0.f,0.f,0.f);
    float4 s2 = make_float4(0.f,0.f,0.f,0.f);
#pragma unroll
    for (int i = 0; i < 4; ++i) {
        s.x += h[i].x; s.y += h[i].y; s.z += h[i].z; s.w += h[i].w;
        s2.x += h[i].x*h[i].x; s2.y += h[i].y*h[i].y;
        s2.z += h[i].z*h[i].z; s2.w += h[i].w*h[i].w;
    }
    __shared__ float4 ls[32][8];
    __shared__ float4 ls2[32][8];
    ls[grp][f] = s; ls2[grp][f] = s2;
    __syncthreads();
    if (threadIdx.x < 32) {
        const int e = threadIdx.x;
        const int fr = e >> 2, j = e & 3;
        float a = 0.f, a2 = 0.f;
#pragma unroll
        for (int g = 0; g < 32; ++g) {
            a  += ((const float*)&ls[g][fr])[j];
            a2 += ((const float*)&ls2[g][fr])[j];
        }
        atomicAdd(&wsum[m * EM + e], a);
        atomicAdd(&wsumsq[m * EM + e], a2);
    }
}

// ---------------------------------------------------------------------------
// K2: fold BN + projection: a[m,e]=istd*gamma*w; g2[row*64+m]=dot(tbl_row,a).
// Reads the f32 table (full precision for the normalized path).
// ---------------------------------------------------------------------------
__global__ __launch_bounds__(256) void k_prep(
    const float* __restrict__ tbl,
    const float* __restrict__ gamma, const float* __restrict__ beta,
    const float* __restrict__ bw, const float* __restrict__ bb,
    const float* __restrict__ wsum, const float* __restrict__ wsumsq,
    float* __restrict__ Cm, float* __restrict__ g2)
{
    const int m    = blockIdx.x >> 2;
    const int part = blockIdx.x & 3;
    __shared__ float a_s[EM];
    if (threadIdx.x < EM) {
        const int e  = threadIdx.x;
        const int ch = m * EM + e;
        const float inv_n = 1.f / (float)B_TOT;
        const float mean = wsum[ch] * inv_n;
        const float var  = wsumsq[ch] * inv_n - mean * mean;
        const float istd = rsqrtf(var + 1e-5f);
        const float g = gamma[ch];
        const float w = bw[ch];
        a_s[e] = istd * g * w;
        float ct = (beta[ch] - mean * istd * g) * w;
#pragma unroll
        for (int off = 16; off > 0; off >>= 1) ct += __shfl_down(ct, off, 32);
        if (e == 0 && part == 0) Cm[m] = bb[m] + ct;
    }
    __syncthreads();

    const float* __restrict__ tblm = tbl + (size_t)m * (TROWS * EM);
    const int row = part * 256 + threadIdx.x;
    const float4* rp = (const float4*)(tblm + row * EM);
    float acc = 0.f;
#pragma unroll
    for (int i = 0; i < 8; ++i) {
        const float4 v = rp[i];
        acc += v.x * a_s[i*4+0] + v.y * a_s[i*4+1]
             + v.z * a_s[i*4+2] + v.w * a_s[i*4+3];
    }
    g2[row * NM + m] = acc;
}

// ---------------------------------------------------------------------------
// K3: out[b,m] = C[m] + sum_t g2[(t*64 + x[b,m*16+t])*64 + m]; plus row sum.
// 64KB slab (quarter of g2) x 4 phases -> 2 blocks/CU co-resident so the
// staging latency of one block hides behind the other's gather phase
// (round-3 used 128KB -> 1 block/CU, fully serialized).
// Grid: 512 blocks x 1024 threads (16 b per block). Slab gather bank =
// m&31 -> 2 lanes/bank = free.
// ---------------------------------------------------------------------------
__global__ __launch_bounds__(1024, 8) void k_out(
    const int* __restrict__ x, const float* __restrict__ g2,
    const float* __restrict__ Cm, float* __restrict__ out)
{
    __shared__ float slab[4 * LF * NM];      // 64KB
    const int tid  = threadIdx.x;
    const int wid  = tid >> 6;               // 0..15
    const int lane = tid & 63;               // = m
    const int b    = blockIdx.x * 16 + wid;

    const int4* xp = (const int4*)(x + (size_t)b * XROW + lane * TT);
    const int4 q0 = xp[0], q1 = xp[1], q2 = xp[2], q3 = xp[3];
    const int idxs[16] = {q0.x,q0.y,q0.z,q0.w, q1.x,q1.y,q1.z,q1.w,
                          q2.x,q2.y,q2.z,q2.w, q3.x,q3.y,q3.z,q3.w};

    float acc = 0.f;
#pragma unroll
    for (int ph = 0; ph < 4; ++ph) {
        if (ph) __syncthreads();             // done reading previous slab
        const float4* src = (const float4*)(g2 + (size_t)ph * (4 * LF * NM));
        float4* dst = (float4*)slab;
#pragma unroll
        for (int j = 0; j < 4; ++j) dst[tid + j * 1024] = src[tid + j * 1024];
        __syncthreads();
#pragma unroll
        for (int tt = 0; tt < 4; ++tt)
            acc += slab[tt * (LF * NM) + idxs[ph * 4 + tt] * NM + lane];
    }

    const float o = acc + Cm[lane];
    float s = o;
#pragma unroll
    for (int off = 32; off > 0; off >>= 1) s += __shfl_down(s, off);
    out[B_TOT + (size_t)b * NM + lane] = o;  // out tensor (B, M)
    if (lane == 0) out[b] = s;               // sum_out (B, 1)
}

// ---------------------------------------------------------------------------
extern "C" void kernel_launch(void* const* d_in, const int* in_sizes, int n_in,
                              void* d_out, int out_size, void* d_ws, size_t ws_size,
                              hipStream_t stream) {
    const int*   x       = (const int*)d_in[0];
    const float* embed_w = (const float*)d_in[1];
    const float* gamma   = (const float*)d_in[2];
    const float* beta    = (const float*)d_in[3];
    const float* bout_w  = (const float*)d_in[4];
    const float* bout_b  = (const float*)d_in[5];
    float* out = (float*)d_out;

    float* ws     = (float*)d_ws;
    float* wsum   = ws;           // 2048 floats
    float* wsumsq = ws + 2048;    // 2048
    float* Cm     = ws + 4096;    // 64
    float* g2     = ws + 4160;    // 65536 (ends at 69696 floats = 278784 B)
    void*  tbl16  = (void*)(ws + 69696);                       // 4MB bf16 table
    const size_t need16 = 69696u * 4u + (size_t)NM * TROWS * EM * 2u;

    // stats accumulators must start at zero (ws is poisoned each launch)
    (void)hipMemsetAsync(wsum, 0, 4096 * sizeof(float), stream);

    if (ws_size >= need16) {
        k_conv<<<dim3(2048), dim3(256), 0, stream>>>((const float4*)embed_w,
                                                     (ushort4*)tbl16);
        k_stats16<<<dim3(2048), dim3(256), 0, stream>>>(x, (const uint4*)tbl16,
                                                        wsum, wsumsq);
    } else {
        k_stats<<<dim3(4096), dim3(256), 0, stream>>>(x, embed_w, wsum, wsumsq);
    }
    k_prep<<<dim3(256),  dim3(256), 0, stream>>>(embed_w, gamma, beta, bout_w,
                                                 bout_b, wsum, wsumsq, Cm, g2);
    k_out <<<dim3(512),  dim3(1024), 0, stream>>>(x, g2, Cm, out);
}

// Round 6
// 116.027 us; speedup vs baseline: 1.2660x; 1.2660x over previous
//
#include <hip/hip_runtime.h>

// Problem constants
constexpr int B_TOT = 8192;      // batch
constexpr int NM    = 64;        // n_models
constexpr int TT    = 16;        // trees per split
constexpr int LF    = 64;        // maxleaf
constexpr int EM    = 32;        // emb dim
constexpr int XROW  = NM * TT;   // 1024 ints per x row
constexpr int TROWS = TT * LF;   // 1024 rows per model table

// pack two f32 -> one dword of two bf16 (RNE): lo in [15:0], hi in [31:16]
__device__ __forceinline__ unsigned bf2(float lo, float hi) {
    unsigned ul = __float_as_uint(lo), uh = __float_as_uint(hi);
    ul += 0x7fffu + ((ul >> 16) & 1u);
    uh += 0x7fffu + ((uh >> 16) & 1u);
    return (ul >> 16) | (uh & 0xffff0000u);
}

__device__ __forceinline__ void accum8(float* h, const uint4 v) {
    // bf16 pair -> f32: lo = u<<16, hi = u & 0xffff0000 (free conversions)
    h[0] += __uint_as_float(v.x << 16);
    h[1] += __uint_as_float(v.x & 0xffff0000u);
    h[2] += __uint_as_float(v.y << 16);
    h[3] += __uint_as_float(v.y & 0xffff0000u);
    h[4] += __uint_as_float(v.z << 16);
    h[5] += __uint_as_float(v.z & 0xffff0000u);
    h[6] += __uint_as_float(v.w << 16);
    h[7] += __uint_as_float(v.w & 0xffff0000u);
}

// ---------------------------------------------------------------------------
// K1: per-channel batch stats, gathering from an LDS-resident bf16 table.
// Evidence: f32 (R3) and bf16 (R4) global-gather versions both sit at
// ~4 cyc per touched row regardless of bytes/instr count -> L1/TA divergent-
// line rate is the wall. LDS gather bypasses it: 537MB total ds_read at
// 128 B/cyc/CU = ~7us floor.
// Block: 512 thr owns model m; stages+converts its 128KB f32 table -> 64KB
// bf16 (4096 uint4) in LDS once; 8 phases x 128 b: x slab (8KB) staged with
// register prefetch; gather = ds_read_b128 (16B = 8 channels, f = tid&3).
// LDS: 64 + 8 + 2 = 74KB -> 2 blocks/CU (16 waves). Grid 512 = 2/CU exact.
// (R5 crash: staging loop ran i<16 -> OOB write at tb[4096..8191]; each
//  uint4 = 2 source float4, so 4096 outputs need exactly i<8.)
// ---------------------------------------------------------------------------
__global__ __launch_bounds__(512, 4) void k_stats_lds(
    const int* __restrict__ x, const float* __restrict__ tbl,
    float* __restrict__ wsum, float* __restrict__ wsumsq)
{
    __shared__ uint4 tb[TROWS * 4];      // 64KB bf16 table [row][quad]
    __shared__ int   xb[128 * 16];       // 8KB x slab: [b_local][t]
    __shared__ float red[2][8][32];      // 2KB reduction scratch

    const int m     = blockIdx.x & 63;
    const int chunk = blockIdx.x >> 6;   // 0..7
    const int tid   = threadIdx.x;
    const int f     = tid & 3;           // channel quad (8 ch)
    const int grp   = tid >> 2;          // 0..127 = b within phase
    const int b0    = chunk * 1024;

    // ---- stage + convert table m: f32 128KB -> bf16 64KB (4096 uint4) ----
    {
        const float4* __restrict__ src = (const float4*)(tbl + (size_t)m * (TROWS * EM));
#pragma unroll
        for (int i = 0; i < 8; ++i) {
            const int o = tid + i * 512;             // uint4 index 0..4095
            const float4 a = src[o * 2];
            const float4 c = src[o * 2 + 1];
            uint4 p;
            p.x = bf2(a.x, a.y); p.y = bf2(a.z, a.w);
            p.z = bf2(c.x, c.y); p.w = bf2(c.z, c.w);
            tb[o] = p;
        }
    }

    // ---- prefetch x for phase 0 (1 int4 per thread = 128 b x 64B) ----
    const int4* __restrict__ xg = (const int4*)(x + (size_t)(b0 + grp) * XROW + m * TT);
    int4 xr = xg[f];

    float s[8], s2[8];
#pragma unroll
    for (int k = 0; k < 8; ++k) { s[k] = 0.f; s2[k] = 0.f; }

    for (int p = 0; p < 8; ++p) {
        __syncthreads();                 // xb free (prev phase consumed) / tb ready
        ((int4*)xb)[grp * 4 + f] = xr;
        if (p < 7) {                     // issue next x load; latency hides behind gather
            const int4* nxt = (const int4*)(x + (size_t)(b0 + (p + 1) * 128 + grp) * XROW + m * TT);
            xr = nxt[f];
        }
        __syncthreads();                 // xb ready

        float h[8];
#pragma unroll
        for (int k = 0; k < 8; ++k) h[k] = 0.f;

#pragma unroll
        for (int tq = 0; tq < 4; ++tq) {
            const int4 q = ((const int4*)xb)[grp * 4 + tq];   // broadcast (4 lanes/addr)
            const int rbase = tq * 256;                       // 64 * (tq*4)
            accum8(h, tb[(q.x + rbase      ) * 4 + f]);
            accum8(h, tb[(q.y + rbase +  64) * 4 + f]);
            accum8(h, tb[(q.z + rbase + 128) * 4 + f]);
            accum8(h, tb[(q.w + rbase + 192) * 4 + f]);
        }
#pragma unroll
        for (int k = 0; k < 8; ++k) { s[k] += h[k]; s2[k] = fmaf(h[k], h[k], s2[k]); }
    }

    // ---- reduce over grp: butterfly within wave (grp bits = lane 2..5) ----
#pragma unroll
    for (int off = 4; off <= 32; off <<= 1) {
#pragma unroll
        for (int k = 0; k < 8; ++k) {
            s[k]  += __shfl_xor(s[k],  off);
            s2[k] += __shfl_xor(s2[k], off);
        }
    }
    const int wave = tid >> 6;
    if ((tid & 63) < 4) {
#pragma unroll
        for (int k = 0; k < 8; ++k) {
            red[0][wave][f * 8 + k] = s[k];
            red[1][wave][f * 8 + k] = s2[k];
        }
    }
    __syncthreads();
    if (tid < 32) {
        float a = 0.f, a2 = 0.f;
#pragma unroll
        for (int w = 0; w < 8; ++w) { a += red[0][w][tid]; a2 += red[1][w][tid]; }
        atomicAdd(&wsum[m * EM + tid], a);
        atomicAdd(&wsumsq[m * EM + tid], a2);
    }
}

// ---------------------------------------------------------------------------
// K2: fold BN + projection: a[m,e]=istd*gamma*w; g2[row*64+m]=dot(tbl_row,a).
// Reads the f32 table (full precision for the normalized path).
// ---------------------------------------------------------------------------
__global__ __launch_bounds__(256) void k_prep(
    const float* __restrict__ tbl,
    const float* __restrict__ gamma, const float* __restrict__ beta,
    const float* __restrict__ bw, const float* __restrict__ bb,
    const float* __restrict__ wsum, const float* __restrict__ wsumsq,
    float* __restrict__ Cm, float* __restrict__ g2)
{
    const int m    = blockIdx.x >> 2;
    const int part = blockIdx.x & 3;
    __shared__ float a_s[EM];
    if (threadIdx.x < EM) {
        const int e  = threadIdx.x;
        const int ch = m * EM + e;
        const float inv_n = 1.f / (float)B_TOT;
        const float mean = wsum[ch] * inv_n;
        const float var  = wsumsq[ch] * inv_n - mean * mean;
        const float istd = rsqrtf(var + 1e-5f);
        const float g = gamma[ch];
        const float w = bw[ch];
        a_s[e] = istd * g * w;
        float ct = (beta[ch] - mean * istd * g) * w;
#pragma unroll
        for (int off = 16; off > 0; off >>= 1) ct += __shfl_down(ct, off, 32);
        if (e == 0 && part == 0) Cm[m] = bb[m] + ct;
    }
    __syncthreads();

    const float* __restrict__ tblm = tbl + (size_t)m * (TROWS * EM);
    const int row = part * 256 + threadIdx.x;
    const float4* rp = (const float4*)(tblm + row * EM);
    float acc = 0.f;
#pragma unroll
    for (int i = 0; i < 8; ++i) {
        const float4 v = rp[i];
        acc += v.x * a_s[i*4+0] + v.y * a_s[i*4+1]
             + v.z * a_s[i*4+2] + v.w * a_s[i*4+3];
    }
    g2[row * NM + m] = acc;
}

// ---------------------------------------------------------------------------
// K3: out[b,m] = C[m] + sum_t g2[(t*64 + x[b,m*16+t])*64 + m]; plus row sum.
// 64KB slab (quarter of g2) x 4 phases -> 2 blocks/CU co-resident.
// Grid: 512 blocks x 1024 threads (16 b per block). Slab gather bank =
// m&31 -> 2 lanes/bank = free.
// ---------------------------------------------------------------------------
__global__ __launch_bounds__(1024, 8) void k_out(
    const int* __restrict__ x, const float* __restrict__ g2,
    const float* __restrict__ Cm, float* __restrict__ out)
{
    __shared__ float slab[4 * LF * NM];      // 64KB
    const int tid  = threadIdx.x;
    const int wid  = tid >> 6;               // 0..15
    const int lane = tid & 63;               // = m
    const int b    = blockIdx.x * 16 + wid;

    const int4* xp = (const int4*)(x + (size_t)b * XROW + lane * TT);
    const int4 q0 = xp[0], q1 = xp[1], q2 = xp[2], q3 = xp[3];
    const int idxs[16] = {q0.x,q0.y,q0.z,q0.w, q1.x,q1.y,q1.z,q1.w,
                          q2.x,q2.y,q2.z,q2.w, q3.x,q3.y,q3.z,q3.w};

    float acc = 0.f;
#pragma unroll
    for (int ph = 0; ph < 4; ++ph) {
        if (ph) __syncthreads();             // done reading previous slab
        const float4* src = (const float4*)(g2 + (size_t)ph * (4 * LF * NM));
        float4* dst = (float4*)slab;
#pragma unroll
        for (int j = 0; j < 4; ++j) dst[tid + j * 1024] = src[tid + j * 1024];
        __syncthreads();
#pragma unroll
        for (int tt = 0; tt < 4; ++tt)
            acc += slab[tt * (LF * NM) + idxs[ph * 4 + tt] * NM + lane];
    }

    const float o = acc + Cm[lane];
    float s = o;
#pragma unroll
    for (int off = 32; off > 0; off >>= 1) s += __shfl_down(s, off);
    out[B_TOT + (size_t)b * NM + lane] = o;  // out tensor (B, M)
    if (lane == 0) out[b] = s;               // sum_out (B, 1)
}

// ---------------------------------------------------------------------------
extern "C" void kernel_launch(void* const* d_in, const int* in_sizes, int n_in,
                              void* d_out, int out_size, void* d_ws, size_t ws_size,
                              hipStream_t stream) {
    const int*   x       = (const int*)d_in[0];
    const float* embed_w = (const float*)d_in[1];
    const float* gamma   = (const float*)d_in[2];
    const float* beta    = (const float*)d_in[3];
    const float* bout_w  = (const float*)d_in[4];
    const float* bout_b  = (const float*)d_in[5];
    float* out = (float*)d_out;

    float* ws     = (float*)d_ws;
    float* wsum   = ws;           // 2048 floats
    float* wsumsq = ws + 2048;    // 2048
    float* Cm     = ws + 4096;    // 64
    float* g2     = ws + 4160;    // 65536

    // stats accumulators must start at zero (ws is poisoned each launch)
    (void)hipMemsetAsync(wsum, 0, 4096 * sizeof(float), stream);

    k_stats_lds<<<dim3(512), dim3(512), 0, stream>>>(x, embed_w, wsum, wsumsq);
    k_prep<<<dim3(256), dim3(256),  0, stream>>>(embed_w, gamma, beta, bout_w,
                                                 bout_b, wsum, wsumsq, Cm, g2);
    k_out <<<dim3(512), dim3(1024), 0, stream>>>(x, g2, Cm, out);
}

// Round 7
// 111.368 us; speedup vs baseline: 1.3189x; 1.0418x over previous
//
#include <hip/hip_runtime.h>
#include <hip/hip_fp16.h>

// Problem constants
constexpr int B_TOT = 8192;      // batch
constexpr int NM    = 64;        // n_models
constexpr int TT    = 16;        // trees per split
constexpr int LF    = 64;        // maxleaf
constexpr int EM    = 32;        // emb dim
constexpr int XROW  = NM * TT;   // 1024 ints per x row
constexpr int TROWS = TT * LF;   // 1024 rows per model table

// ---------------------------------------------------------------------------
// K1: per-channel batch stats, gathering from an LDS-resident f16 table.
// R6 post-mortem: bf16 version was VALU-bound (~2700 instr/thread; unpack =
// 2 ops/channel) + 16 phase barriers. f16 accumulates with native
// v_pk_add_f16 straight from ds_read_b128 (4 VALU per 8 channels, no unpack)
// and x is read per-thread (4 lanes share one 64B line -> L1 broadcast),
// killing the x slab and all phase barriers.
// Block: 512 thr owns model m; stages+converts 128KB f32 table -> 64KB f16
// in LDS once; each thread: 8 b's, 16 ds_read_b128 per b (quad f = tid&3).
// LDS: 64 + 2 KB -> 2 blocks/CU (16 waves). Grid 512 = 64 m x 8 chunks.
// ---------------------------------------------------------------------------
__global__ __launch_bounds__(512, 4) void k_stats_f16(
    const int* __restrict__ x, const float* __restrict__ tbl,
    float* __restrict__ wsum, float* __restrict__ wsumsq)
{
    __shared__ uint4 tb[TROWS * 4];      // 64KB f16 table: [row][quad of 8 ch]
    __shared__ float red[2][8][32];      // 2KB reduction scratch

    const int m     = blockIdx.x & 63;
    const int chunk = blockIdx.x >> 6;   // 0..7
    const int tid   = threadIdx.x;
    const int f     = tid & 3;           // channel quad (8 ch)
    const int grp   = tid >> 2;          // 0..127 = b within iteration
    const int b0    = chunk * 1024;

    // ---- stage + convert table m: f32 128KB -> f16 64KB (4096 uint4) ----
    {
        const float4* __restrict__ src = (const float4*)(tbl + (size_t)m * (TROWS * EM));
#pragma unroll
        for (int i = 0; i < 8; ++i) {
            const int o = tid + i * 512;             // uint4 index 0..4095
            const float4 a = src[o * 2];
            const float4 c = src[o * 2 + 1];
            uint4 p;
            __half2 h0 = __floats2half2_rn(a.x, a.y);
            __half2 h1 = __floats2half2_rn(a.z, a.w);
            __half2 h2 = __floats2half2_rn(c.x, c.y);
            __half2 h3 = __floats2half2_rn(c.z, c.w);
            p.x = *(unsigned*)&h0; p.y = *(unsigned*)&h1;
            p.z = *(unsigned*)&h2; p.w = *(unsigned*)&h3;
            tb[o] = p;
        }
    }

    // ---- prefetch x for iteration 0 (whole row for this thread's b) ----
    const int4* xp = (const int4*)(x + (size_t)(b0 + grp) * XROW + m * TT);
    int4 xa = xp[0], xb_ = xp[1], xc = xp[2], xd = xp[3];

    float s[8], s2[8];
#pragma unroll
    for (int k = 0; k < 8; ++k) { s[k] = 0.f; s2[k] = 0.f; }

    __syncthreads();                     // tb ready

    for (int p = 0; p < 8; ++p) {
        int4 na, nb, nc, nd;
        if (p < 7) {                     // issue next b's x row; hides behind gather
            const int4* np = (const int4*)(x + (size_t)(b0 + (p + 1) * 128 + grp) * XROW + m * TT);
            na = np[0]; nb = np[1]; nc = np[2]; nd = np[3];
        }

        __half2 h[4];                    // 8 channels (quad f)
#pragma unroll
        for (int k = 0; k < 4; ++k) h[k] = __half2(__half(0.f), __half(0.f));

#pragma unroll
        for (int tq = 0; tq < 4; ++tq) {
            const int4 q = (tq == 0) ? xa : (tq == 1) ? xb_ : (tq == 2) ? xc : xd;
            const int rbase = tq * 256;  // 64 * (tq*4)
            const uint4 v0 = tb[(q.x + rbase      ) * 4 + f];
            const uint4 v1 = tb[(q.y + rbase +  64) * 4 + f];
            const uint4 v2 = tb[(q.z + rbase + 128) * 4 + f];
            const uint4 v3 = tb[(q.w + rbase + 192) * 4 + f];
            h[0] = __hadd2(h[0], __hadd2(__hadd2(*(const __half2*)&v0.x, *(const __half2*)&v1.x),
                                         __hadd2(*(const __half2*)&v2.x, *(const __half2*)&v3.x)));
            h[1] = __hadd2(h[1], __hadd2(__hadd2(*(const __half2*)&v0.y, *(const __half2*)&v1.y),
                                         __hadd2(*(const __half2*)&v2.y, *(const __half2*)&v3.y)));
            h[2] = __hadd2(h[2], __hadd2(__hadd2(*(const __half2*)&v0.z, *(const __half2*)&v1.z),
                                         __hadd2(*(const __half2*)&v2.z, *(const __half2*)&v3.z)));
            h[3] = __hadd2(h[3], __hadd2(__hadd2(*(const __half2*)&v0.w, *(const __half2*)&v1.w),
                                         __hadd2(*(const __half2*)&v2.w, *(const __half2*)&v3.w)));
        }

#pragma unroll
        for (int k = 0; k < 4; ++k) {
            const float lo = __low2float(h[k]);
            const float hi = __high2float(h[k]);
            s[2*k]   += lo;  s2[2*k]   = fmaf(lo, lo, s2[2*k]);
            s[2*k+1] += hi;  s2[2*k+1] = fmaf(hi, hi, s2[2*k+1]);
        }

        xa = na; xb_ = nb; xc = nc; xd = nd;
    }

    // ---- reduce over grp: butterfly within wave (grp bits = lane 2..5) ----
#pragma unroll
    for (int off = 4; off <= 32; off <<= 1) {
#pragma unroll
        for (int k = 0; k < 8; ++k) {
            s[k]  += __shfl_xor(s[k],  off);
            s2[k] += __shfl_xor(s2[k], off);
        }
    }
    const int wave = tid >> 6;
    if ((tid & 63) < 4) {
#pragma unroll
        for (int k = 0; k < 8; ++k) {
            red[0][wave][f * 8 + k] = s[k];
            red[1][wave][f * 8 + k] = s2[k];
        }
    }
    __syncthreads();
    if (tid < 32) {
        float a = 0.f, a2 = 0.f;
#pragma unroll
        for (int w = 0; w < 8; ++w) { a += red[0][w][tid]; a2 += red[1][w][tid]; }
        atomicAdd(&wsum[m * EM + tid], a);
        atomicAdd(&wsumsq[m * EM + tid], a2);
    }
}

// ---------------------------------------------------------------------------
// K2: fold BN + projection: a[m,e]=istd*gamma*w; g2[row*64+m]=dot(tbl_row,a).
// Reads the f32 table (full precision for the normalized path).
// ---------------------------------------------------------------------------
__global__ __launch_bounds__(256) void k_prep(
    const float* __restrict__ tbl,
    const float* __restrict__ gamma, const float* __restrict__ beta,
    const float* __restrict__ bw, const float* __restrict__ bb,
    const float* __restrict__ wsum, const float* __restrict__ wsumsq,
    float* __restrict__ Cm, float* __restrict__ g2)
{
    const int m    = blockIdx.x >> 2;
    const int part = blockIdx.x & 3;
    __shared__ float a_s[EM];
    if (threadIdx.x < EM) {
        const int e  = threadIdx.x;
        const int ch = m * EM + e;
        const float inv_n = 1.f / (float)B_TOT;
        const float mean = wsum[ch] * inv_n;
        const float var  = wsumsq[ch] * inv_n - mean * mean;
        const float istd = rsqrtf(var + 1e-5f);
        const float g = gamma[ch];
        const float w = bw[ch];
        a_s[e] = istd * g * w;
        float ct = (beta[ch] - mean * istd * g) * w;
#pragma unroll
        for (int off = 16; off > 0; off >>= 1) ct += __shfl_down(ct, off, 32);
        if (e == 0 && part == 0) Cm[m] = bb[m] + ct;
    }
    __syncthreads();

    const float* __restrict__ tblm = tbl + (size_t)m * (TROWS * EM);
    const int row = part * 256 + threadIdx.x;
    const float4* rp = (const float4*)(tblm + row * EM);
    float acc = 0.f;
#pragma unroll
    for (int i = 0; i < 8; ++i) {
        const float4 v = rp[i];
        acc += v.x * a_s[i*4+0] + v.y * a_s[i*4+1]
             + v.z * a_s[i*4+2] + v.w * a_s[i*4+3];
    }
    g2[row * NM + m] = acc;
}

// ---------------------------------------------------------------------------
// K3: out[b,m] = C[m] + sum_t g2[(t*64 + x[b,m*16+t])*64 + m]; plus row sum.
// 64KB slab (quarter of g2) x 4 phases -> 2 blocks/CU co-resident.
// Grid: 512 blocks x 1024 threads (16 b per block). Slab gather bank =
// m&31 -> 2 lanes/bank = free.
// ---------------------------------------------------------------------------
__global__ __launch_bounds__(1024, 8) void k_out(
    const int* __restrict__ x, const float* __restrict__ g2,
    const float* __restrict__ Cm, float* __restrict__ out)
{
    __shared__ float slab[4 * LF * NM];      // 64KB
    const int tid  = threadIdx.x;
    const int wid  = tid >> 6;               // 0..15
    const int lane = tid & 63;               // = m
    const int b    = blockIdx.x * 16 + wid;

    const int4* xp = (const int4*)(x + (size_t)b * XROW + lane * TT);
    const int4 q0 = xp[0], q1 = xp[1], q2 = xp[2], q3 = xp[3];
    const int idxs[16] = {q0.x,q0.y,q0.z,q0.w, q1.x,q1.y,q1.z,q1.w,
                          q2.x,q2.y,q2.z,q2.w, q3.x,q3.y,q3.z,q3.w};

    float acc = 0.f;
#pragma unroll
    for (int ph = 0; ph < 4; ++ph) {
        if (ph) __syncthreads();             // done reading previous slab
        const float4* src = (const float4*)(g2 + (size_t)ph * (4 * LF * NM));
        float4* dst = (float4*)slab;
#pragma unroll
        for (int j = 0; j < 4; ++j) dst[tid + j * 1024] = src[tid + j * 1024];
        __syncthreads();
#pragma unroll
        for (int tt = 0; tt < 4; ++tt)
            acc += slab[tt * (LF * NM) + idxs[ph * 4 + tt] * NM + lane];
    }

    const float o = acc + Cm[lane];
    float s = o;
#pragma unroll
    for (int off = 32; off > 0; off >>= 1) s += __shfl_down(s, off);
    out[B_TOT + (size_t)b * NM + lane] = o;  // out tensor (B, M)
    if (lane == 0) out[b] = s;               // sum_out (B, 1)
}

// ---------------------------------------------------------------------------
extern "C" void kernel_launch(void* const* d_in, const int* in_sizes, int n_in,
                              void* d_out, int out_size, void* d_ws, size_t ws_size,
                              hipStream_t stream) {
    const int*   x       = (const int*)d_in[0];
    const float* embed_w = (const float*)d_in[1];
    const float* gamma   = (const float*)d_in[2];
    const float* beta    = (const float*)d_in[3];
    const float* bout_w  = (const float*)d_in[4];
    const float* bout_b  = (const float*)d_in[5];
    float* out = (float*)d_out;

    float* ws     = (float*)d_ws;
    float* wsum   = ws;           // 2048 floats
    float* wsumsq = ws + 2048;    // 2048
    float* Cm     = ws + 4096;    // 64
    float* g2     = ws + 4160;    // 65536

    // stats accumulators must start at zero (ws is poisoned each launch)
    (void)hipMemsetAsync(wsum, 0, 4096 * sizeof(float), stream);

    k_stats_f16<<<dim3(512), dim3(512), 0, stream>>>(x, embed_w, wsum, wsumsq);
    k_prep<<<dim3(256), dim3(256),  0, stream>>>(embed_w, gamma, beta, bout_w,
                                                 bout_b, wsum, wsumsq, Cm, g2);
    k_out <<<dim3(512), dim3(1024), 0, stream>>>(x, g2, Cm, out);
}

// Round 8
// 108.008 us; speedup vs baseline: 1.3600x; 1.0311x over previous
//
#include <hip/hip_runtime.h>
#include <hip/hip_fp16.h>

// Problem constants
constexpr int B_TOT = 8192;      // batch
constexpr int NM    = 64;        // n_models
constexpr int TT    = 16;        // trees per split
constexpr int LF    = 64;        // maxleaf
constexpr int EM    = 32;        // emb dim
constexpr int XROW  = NM * TT;   // 1024 ints per x row
constexpr int TROWS = TT * LF;   // 1024 rows per model table

// Broadcast quad-lane TQ's int4 to all 4 lanes of each quad via DPP
// (VALU pipe — does NOT load the LDS pipe like __shfl/ds_bpermute would).
template<int TQ>
__device__ __forceinline__ int4 qbcast(int4 v) {
    constexpr int c = TQ * 0x55;          // quad_perm [TQ,TQ,TQ,TQ]
    int4 r;
    r.x = __builtin_amdgcn_mov_dpp(v.x, c, 0xf, 0xf, true);
    r.y = __builtin_amdgcn_mov_dpp(v.y, c, 0xf, 0xf, true);
    r.z = __builtin_amdgcn_mov_dpp(v.z, c, 0xf, 0xf, true);
    r.w = __builtin_amdgcn_mov_dpp(v.w, c, 0xf, 0xf, true);
    return r;
}

__device__ __forceinline__ __half2 H2(unsigned u) { return *(const __half2*)&u; }

// ---------------------------------------------------------------------------
// K1: per-channel batch stats from an LDS-resident f16 table.
// R7 residual analysis: x-path cost — 4 loads/phase with 4x lane redundancy
// = 64 divergent-line touches per wave-phase. Now: ONE int4 load per lane
// (quad lane f owns t-quad f -> 16 unique lines, 1 instr), indices broadcast
// within the quad by v_mov_dpp quad_perm (VALU). 4x fewer TA line touches.
// Stats epilogue writes per-(chunk,m) partials (no atomics, no memset).
// Block: 512 thr owns model m; 64KB f16 table in LDS; 8 phases x 128 b.
// LDS: 64 + 2 KB -> 2 blocks/CU (16 waves). Grid 512 = 64 m x 8 chunks.
// ---------------------------------------------------------------------------
__global__ __launch_bounds__(512, 4) void k_stats_f16(
    const int* __restrict__ x, const float* __restrict__ tbl,
    float* __restrict__ psum, float* __restrict__ psq)
{
    __shared__ uint4 tb[TROWS * 4];      // 64KB f16 table: [row][quad of 8 ch]
    __shared__ float red[2][8][32];      // 2KB reduction scratch

    const int m     = blockIdx.x & 63;
    const int chunk = blockIdx.x >> 6;   // 0..7
    const int tid   = threadIdx.x;
    const int f     = tid & 3;           // channel quad (8 ch) AND t-quad owned
    const int grp   = tid >> 2;          // 0..127 = b within phase
    const int b0    = chunk * 1024;

    // ---- stage + convert table m: f32 128KB -> f16 64KB (4096 uint4) ----
    {
        const float4* __restrict__ src = (const float4*)(tbl + (size_t)m * (TROWS * EM));
#pragma unroll
        for (int i = 0; i < 8; ++i) {
            const int o = tid + i * 512;             // uint4 index 0..4095
            const float4 a = src[o * 2];
            const float4 c = src[o * 2 + 1];
            uint4 p;
            __half2 h0 = __floats2half2_rn(a.x, a.y);
            __half2 h1 = __floats2half2_rn(a.z, a.w);
            __half2 h2 = __floats2half2_rn(c.x, c.y);
            __half2 h3 = __floats2half2_rn(c.z, c.w);
            p.x = *(unsigned*)&h0; p.y = *(unsigned*)&h1;
            p.z = *(unsigned*)&h2; p.w = *(unsigned*)&h3;
            tb[o] = p;
        }
    }

    // ---- prefetch x for phase 0: ONE int4 per lane (t-quad f of b0+grp) ----
    int4 xr = ((const int4*)(x + (size_t)(b0 + grp) * XROW + m * TT))[f];

    float s[8], s2[8];
#pragma unroll
    for (int k = 0; k < 8; ++k) { s[k] = 0.f; s2[k] = 0.f; }

    __syncthreads();                     // tb ready

    for (int p = 0; p < 8; ++p) {
        int4 nxt;
        if (p < 7)                       // next phase's x; hides behind gather
            nxt = ((const int4*)(x + (size_t)(b0 + (p + 1) * 128 + grp) * XROW + m * TT))[f];

        // all 16 tree indices of this quad's b, via quad broadcast
        const int4 q0 = qbcast<0>(xr);
        const int4 q1 = qbcast<1>(xr);
        const int4 q2 = qbcast<2>(xr);
        const int4 q3 = qbcast<3>(xr);

        __half2 h0 = __half2(__half(0.f), __half(0.f));
        __half2 h1 = h0, h2 = h0, h3 = h0;

#define GATH(Q, RB)                                                          \
        {                                                                    \
            const uint4 a0 = tb[((Q).x + RB      ) * 4 + f];                 \
            const uint4 a1 = tb[((Q).y + RB +  64) * 4 + f];                 \
            const uint4 a2 = tb[((Q).z + RB + 128) * 4 + f];                 \
            const uint4 a3 = tb[((Q).w + RB + 192) * 4 + f];                 \
            h0 = __hadd2(h0, __hadd2(__hadd2(H2(a0.x), H2(a1.x)),            \
                                     __hadd2(H2(a2.x), H2(a3.x))));          \
            h1 = __hadd2(h1, __hadd2(__hadd2(H2(a0.y), H2(a1.y)),            \
                                     __hadd2(H2(a2.y), H2(a3.y))));          \
            h2 = __hadd2(h2, __hadd2(__hadd2(H2(a0.z), H2(a1.z)),            \
                                     __hadd2(H2(a2.z), H2(a3.z))));          \
            h3 = __hadd2(h3, __hadd2(__hadd2(H2(a0.w), H2(a1.w)),            \
                                     __hadd2(H2(a2.w), H2(a3.w))));          \
        }
        GATH(q0, 0) GATH(q1, 256) GATH(q2, 512) GATH(q3, 768)
#undef GATH

        const __half2 hv[4] = {h0, h1, h2, h3};
#pragma unroll
        for (int k = 0; k < 4; ++k) {
            const float lo = __low2float(hv[k]);
            const float hi = __high2float(hv[k]);
            s[2*k]   += lo;  s2[2*k]   = fmaf(lo, lo, s2[2*k]);
            s[2*k+1] += hi;  s2[2*k+1] = fmaf(hi, hi, s2[2*k+1]);
        }
        xr = nxt;
    }

    // ---- reduce over grp: butterfly within wave (grp bits = lane 2..5) ----
#pragma unroll
    for (int off = 4; off <= 32; off <<= 1) {
#pragma unroll
        for (int k = 0; k < 8; ++k) {
            s[k]  += __shfl_xor(s[k],  off);
            s2[k] += __shfl_xor(s2[k], off);
        }
    }
    const int wave = tid >> 6;
    if ((tid & 63) < 4) {
#pragma unroll
        for (int k = 0; k < 8; ++k) {
            red[0][wave][f * 8 + k] = s[k];
            red[1][wave][f * 8 + k] = s2[k];
        }
    }
    __syncthreads();
    if (tid < 32) {
        float a = 0.f, a2 = 0.f;
#pragma unroll
        for (int w = 0; w < 8; ++w) { a += red[0][w][tid]; a2 += red[1][w][tid]; }
        psum[(chunk * NM + m) * EM + tid] = a;   // per-(chunk,m) partials:
        psq [(chunk * NM + m) * EM + tid] = a2;  // no atomics, no memset
    }
}

// ---------------------------------------------------------------------------
// K2: sum the 8 chunk-partials, fold BN + projection:
//   a[m,e]=istd*gamma*w; C[m]=bout_b[m]+sum_e (beta-mean*istd*gamma)*w
//   g2[row*64+m] = dot(tbl[m,row,:], a[m,:])
// Grid: 256 blocks = 64 m x 4 row-quarters, 256 threads.
// ---------------------------------------------------------------------------
__global__ __launch_bounds__(256) void k_prep(
    const float* __restrict__ tbl,
    const float* __restrict__ gamma, const float* __restrict__ beta,
    const float* __restrict__ bw, const float* __restrict__ bb,
    const float* __restrict__ psum, const float* __restrict__ psq,
    float* __restrict__ Cm, float* __restrict__ g2)
{
    const int m    = blockIdx.x >> 2;
    const int part = blockIdx.x & 3;
    __shared__ float a_s[EM];
    if (threadIdx.x < EM) {
        const int e  = threadIdx.x;
        const int ch = m * EM + e;
        float sum = 0.f, sq = 0.f;
#pragma unroll
        for (int c = 0; c < 8; ++c) {
            sum += psum[(c * NM + m) * EM + e];
            sq  += psq [(c * NM + m) * EM + e];
        }
        const float inv_n = 1.f / (float)B_TOT;
        const float mean = sum * inv_n;
        const float var  = sq * inv_n - mean * mean;
        const float istd = rsqrtf(var + 1e-5f);
        const float g = gamma[ch];
        const float w = bw[ch];
        a_s[e] = istd * g * w;
        float ct = (beta[ch] - mean * istd * g) * w;
#pragma unroll
        for (int off = 16; off > 0; off >>= 1) ct += __shfl_down(ct, off, 32);
        if (e == 0 && part == 0) Cm[m] = bb[m] + ct;
    }
    __syncthreads();

    const float* __restrict__ tblm = tbl + (size_t)m * (TROWS * EM);
    const int row = part * 256 + threadIdx.x;
    const float4* rp = (const float4*)(tblm + row * EM);
    float acc = 0.f;
#pragma unroll
    for (int i = 0; i < 8; ++i) {
        const float4 v = rp[i];
        acc += v.x * a_s[i*4+0] + v.y * a_s[i*4+1]
             + v.z * a_s[i*4+2] + v.w * a_s[i*4+3];
    }
    g2[row * NM + m] = acc;
}

// ---------------------------------------------------------------------------
// K3: out[b,m] = C[m] + sum_t g2[(t*64 + x[b,m*16+t])*64 + m]; plus row sum.
// 64KB slab (quarter of g2) x 4 phases -> 2 blocks/CU co-resident.
// Grid: 512 blocks x 1024 threads (16 b per block). Slab gather bank =
// m&31 -> 2 lanes/bank = free.
// ---------------------------------------------------------------------------
__global__ __launch_bounds__(1024, 8) void k_out(
    const int* __restrict__ x, const float* __restrict__ g2,
    const float* __restrict__ Cm, float* __restrict__ out)
{
    __shared__ float slab[4 * LF * NM];      // 64KB
    const int tid  = threadIdx.x;
    const int wid  = tid >> 6;               // 0..15
    const int lane = tid & 63;               // = m
    const int b    = blockIdx.x * 16 + wid;

    const int4* xp = (const int4*)(x + (size_t)b * XROW + lane * TT);
    const int4 q0 = xp[0], q1 = xp[1], q2 = xp[2], q3 = xp[3];
    const int idxs[16] = {q0.x,q0.y,q0.z,q0.w, q1.x,q1.y,q1.z,q1.w,
                          q2.x,q2.y,q2.z,q2.w, q3.x,q3.y,q3.z,q3.w};

    float acc = 0.f;
#pragma unroll
    for (int ph = 0; ph < 4; ++ph) {
        if (ph) __syncthreads();             // done reading previous slab
        const float4* src = (const float4*)(g2 + (size_t)ph * (4 * LF * NM));
        float4* dst = (float4*)slab;
#pragma unroll
        for (int j = 0; j < 4; ++j) dst[tid + j * 1024] = src[tid + j * 1024];
        __syncthreads();
#pragma unroll
        for (int tt = 0; tt < 4; ++tt)
            acc += slab[tt * (LF * NM) + idxs[ph * 4 + tt] * NM + lane];
    }

    const float o = acc + Cm[lane];
    float s = o;
#pragma unroll
    for (int off = 32; off > 0; off >>= 1) s += __shfl_down(s, off);
    out[B_TOT + (size_t)b * NM + lane] = o;  // out tensor (B, M)
    if (lane == 0) out[b] = s;               // sum_out (B, 1)
}

// ---------------------------------------------------------------------------
extern "C" void kernel_launch(void* const* d_in, const int* in_sizes, int n_in,
                              void* d_out, int out_size, void* d_ws, size_t ws_size,
                              hipStream_t stream) {
    const int*   x       = (const int*)d_in[0];
    const float* embed_w = (const float*)d_in[1];
    const float* gamma   = (const float*)d_in[2];
    const float* beta    = (const float*)d_in[3];
    const float* bout_w  = (const float*)d_in[4];
    const float* bout_b  = (const float*)d_in[5];
    float* out = (float*)d_out;

    float* ws   = (float*)d_ws;
    float* Cm   = ws;                 // 64
    float* g2   = ws + 64;            // 65536
    float* psum = ws + 64 + 65536;    // 8 chunks x 64 m x 32 e = 16384
    float* psq  = psum + 16384;       // 16384   (total ~392KB)

    k_stats_f16<<<dim3(512), dim3(512), 0, stream>>>(x, embed_w, psum, psq);
    k_prep<<<dim3(256), dim3(256),  0, stream>>>(embed_w, gamma, beta, bout_w,
                                                 bout_b, psum, psq, Cm, g2);
    k_out <<<dim3(512), dim3(1024), 0, stream>>>(x, g2, Cm, out);
}